// Round 6
// baseline (737.798 us; speedup 1.0000x reference)
//
#include <hip/hip_runtime.h>

// ---------- types ----------
typedef __bf16 bf16x8 __attribute__((ext_vector_type(8)));
typedef __bf16 bf16x4v __attribute__((ext_vector_type(4)));
typedef float  f32x4  __attribute__((ext_vector_type(4)));

#define LDS_AS(p) ((__attribute__((address_space(3))) void*)(p))
#define GLB_AS(p) ((const __attribute__((address_space(1))) void*)(p))

// ---------- batched weight f32 -> bf16 transposed (+ plain copy of W1) ------
struct TP { const float* s[7]; __bf16* d[7]; __bf16* w1b; };
__global__ __launch_bounds__(256) void transpose_convert_all(TP p) {
  const float* __restrict__ W = p.s[blockIdx.z];
  __bf16* __restrict__ Wt = p.d[blockIdx.z];
  __shared__ float tile[32][33];
  const int tx = threadIdx.x & 31, ty = threadIdx.x >> 5;
  const int n0 = blockIdx.x * 32, k0 = blockIdx.y * 32;
#pragma unroll
  for (int j = 0; j < 4; ++j)
    tile[ty + j * 8][tx] = W[(size_t)(k0 + ty + j * 8) * 2048 + n0 + tx];
  __syncthreads();
#pragma unroll
  for (int j = 0; j < 4; ++j)
    Wt[(size_t)(n0 + ty + j * 8) * 2048 + k0 + tx] = (__bf16)tile[tx][ty + j * 8];
  if (blockIdx.z == 4) {  // also non-transposed bf16 copy of W1
#pragma unroll
    for (int j = 0; j < 4; ++j)
      p.w1b[(size_t)(k0 + ty + j * 8) * 2048 + n0 + tx] = (__bf16)tile[ty + j * 8][tx];
  }
}

// ---------- interleave BtFFN rows: [W1t 64 | W12t 64] per 128-row tile ------
__global__ __launch_bounds__(256) void ffn_interleave(
    const __bf16* __restrict__ W1t, const __bf16* __restrict__ W12t,
    __bf16* __restrict__ BtFFN) {
  const int r = blockIdx.x;
  const int t = r >> 7, c = r & 127;
  const __bf16* src = (c < 64) ? (W1t + (size_t)(t * 64 + c) * 2048)
                               : (W12t + (size_t)(t * 64 + (c - 64)) * 2048);
  ((uint4*)(BtFFN + (size_t)r * 2048))[threadIdx.x] = ((const uint4*)src)[threadIdx.x];
}

// ---------- RMSNorm: f32 in -> bf16 out, D=2048, one block per row ----------
__global__ __launch_bounds__(256) void rmsnorm_k(
    const float* __restrict__ x, const float* __restrict__ scale,
    __bf16* __restrict__ out) {
  const int row = blockIdx.x, t = threadIdx.x;
  const float4* xr = (const float4*)(x + (size_t)row * 2048);
  float4 a = xr[t], b2 = xr[t + 256];
  float ss = a.x * a.x + a.y * a.y + a.z * a.z + a.w * a.w +
             b2.x * b2.x + b2.y * b2.y + b2.z * b2.z + b2.w * b2.w;
#pragma unroll
  for (int ofs = 32; ofs; ofs >>= 1) ss += __shfl_xor(ss, ofs, 64);
  __shared__ float red[4];
  if ((t & 63) == 0) red[t >> 6] = ss;
  __syncthreads();
  ss = red[0] + red[1] + red[2] + red[3];
  const float rs = rsqrtf(ss * (1.f / 2048.f) + 1e-5f);
  const float4* sr = (const float4*)scale;
  float4 s1 = sr[t], s2 = sr[t + 256];
  __bf16* orow = out + (size_t)row * 2048;
  orow[t * 4 + 0] = (__bf16)(a.x * rs * s1.x);
  orow[t * 4 + 1] = (__bf16)(a.y * rs * s1.y);
  orow[t * 4 + 2] = (__bf16)(a.z * rs * s1.z);
  orow[t * 4 + 3] = (__bf16)(a.w * rs * s1.w);
  orow[(t + 256) * 4 + 0] = (__bf16)(b2.x * rs * s2.x);
  orow[(t + 256) * 4 + 1] = (__bf16)(b2.y * rs * s2.y);
  orow[(t + 256) * 4 + 2] = (__bf16)(b2.z * rs * s2.z);
  orow[(t + 256) * 4 + 3] = (__bf16)(b2.w * rs * s2.w);
}

// ---------- GEMM 128x128: C[M,N] = A[M,K] @ Bt[N,K]^T, dbuf ----------
template <bool OUTF32, bool HASBIAS, bool HASRES>
__global__ __launch_bounds__(256) void gemm_bt(
    const __bf16* __restrict__ A, const __bf16* __restrict__ Bt,
    const float* __restrict__ bias, const float* __restrict__ res,
    void* __restrict__ Cout, int M, int N, int Kd) {
  __shared__ __attribute__((aligned(16))) __bf16 As[2][128 * 32];
  __shared__ __attribute__((aligned(16))) __bf16 Bs[2][128 * 32];
  const int tid = threadIdx.x;
  const int w = tid >> 6, l = tid & 63;
  const int M0 = blockIdx.y * 128, N0 = blockIdx.x * 128;
  const int wr = w >> 1, wc = w & 1;
  const int lm = l & 15, lq = l >> 4;

  f32x4 acc[4][4];
#pragma unroll
  for (int mt = 0; mt < 4; ++mt)
#pragma unroll
    for (int nt = 0; nt < 4; ++nt)
#pragma unroll
      for (int e = 0; e < 4; ++e) acc[mt][nt][e] = 0.f;

  const int srow = l >> 2, sk = (l & 3) * 16;
  const int nIt = Kd >> 5;

  auto stage = [&](int k0, int bsel) {
#pragma unroll
    for (int i = 0; i < 2; ++i) {
      const int c = w * 2 + i;
      const char* ga = (const char*)(A + (size_t)(M0 + c * 16 + srow) * Kd + k0) + sk;
      const char* gb = (const char*)(Bt + (size_t)(N0 + c * 16 + srow) * Kd + k0) + sk;
      __builtin_amdgcn_global_load_lds(GLB_AS(ga), LDS_AS(((char*)As[bsel]) + c * 1024), 16, 0, 0);
      __builtin_amdgcn_global_load_lds(GLB_AS(gb), LDS_AS(((char*)Bs[bsel]) + c * 1024), 16, 0, 0);
    }
  };

  stage(0, 0);
  for (int it = 0; it < nIt; ++it) {
    __syncthreads();
    if (it + 1 < nIt) stage((it + 1) * 32, (it + 1) & 1);
    const __bf16* Ab = As[it & 1];
    const __bf16* Bb = Bs[it & 1];
    bf16x8 af[4], bfr[4];
#pragma unroll
    for (int mt = 0; mt < 4; ++mt)
      af[mt] = *(const bf16x8*)(Ab + (wr * 64 + mt * 16 + lm) * 32 + lq * 8);
#pragma unroll
    for (int nt = 0; nt < 4; ++nt)
      bfr[nt] = *(const bf16x8*)(Bb + (wc * 64 + nt * 16 + lm) * 32 + lq * 8);
#pragma unroll
    for (int mt = 0; mt < 4; ++mt)
#pragma unroll
      for (int nt = 0; nt < 4; ++nt)
        acc[mt][nt] = __builtin_amdgcn_mfma_f32_16x16x32_bf16(af[mt], bfr[nt], acc[mt][nt], 0, 0, 0);
  }

  const int lr = lq * 4;
#pragma unroll
  for (int mt = 0; mt < 4; ++mt) {
#pragma unroll
    for (int nt = 0; nt < 4; ++nt) {
      const int col = N0 + wc * 64 + nt * 16 + lm;
      float bv = 0.f;
      if (HASBIAS) bv = bias[col];
#pragma unroll
      for (int i = 0; i < 4; ++i) {
        const int row = M0 + wr * 64 + mt * 16 + lr + i;
        const size_t off = (size_t)row * N + col;
        float v = acc[mt][nt][i] + bv;
        if (HASRES) v += res[off];
        if (OUTF32) ((float*)Cout)[off] = v;
        else ((__bf16*)Cout)[off] = (__bf16)v;
      }
    }
  }
}

// ---------- fused QKV GEMM, 256x128 tile, 4 waves x (4x8) accs ----------
__global__ __launch_bounds__(256) void gemm_qkv(
    const __bf16* __restrict__ A, const __bf16* __restrict__ Bt,
    const float* __restrict__ bq, const float* __restrict__ bk,
    const float* __restrict__ bv,
    __bf16* __restrict__ Qout, __bf16* __restrict__ Kout,
    __bf16* __restrict__ Vtout, int Kd) {
  __shared__ __attribute__((aligned(16))) __bf16 As[2][256 * 32];  // 16 KB x2
  __shared__ __attribute__((aligned(16))) __bf16 Bs[2][128 * 32];  // 8 KB x2
  const int tid = threadIdx.x;
  const int w = tid >> 6, l = tid & 63;
  const int M0 = blockIdx.y * 256, N0 = blockIdx.x * 128;
  const int lm = l & 15, lq = l >> 4;

  f32x4 acc[4][8];
#pragma unroll
  for (int mt = 0; mt < 4; ++mt)
#pragma unroll
    for (int nt = 0; nt < 8; ++nt)
#pragma unroll
      for (int e = 0; e < 4; ++e) acc[mt][nt][e] = 0.f;

  const int srow = l >> 2, sk = (l & 3) * 16;
  const int nIt = Kd >> 5;

  auto stage = [&](int k0, int bsel) {
#pragma unroll
    for (int i = 0; i < 4; ++i) {  // A: 16 chunks of 16 rows
      const int c = w * 4 + i;
      const char* ga = (const char*)(A + (size_t)(M0 + c * 16 + srow) * Kd + k0) + sk;
      __builtin_amdgcn_global_load_lds(GLB_AS(ga), LDS_AS(((char*)As[bsel]) + c * 1024), 16, 0, 0);
    }
#pragma unroll
    for (int i = 0; i < 2; ++i) {  // B: 8 chunks
      const int c = w * 2 + i;
      const char* gb = (const char*)(Bt + (size_t)(N0 + c * 16 + srow) * Kd + k0) + sk;
      __builtin_amdgcn_global_load_lds(GLB_AS(gb), LDS_AS(((char*)Bs[bsel]) + c * 1024), 16, 0, 0);
    }
  };

  stage(0, 0);
  for (int it = 0; it < nIt; ++it) {
    __syncthreads();
    if (it + 1 < nIt) stage((it + 1) * 32, (it + 1) & 1);
    const __bf16* Ab = As[it & 1];
    const __bf16* Bb = Bs[it & 1];
    bf16x8 af[4], bfr[8];
#pragma unroll
    for (int mt = 0; mt < 4; ++mt)
      af[mt] = *(const bf16x8*)(Ab + (w * 64 + mt * 16 + lm) * 32 + lq * 8);
#pragma unroll
    for (int nt = 0; nt < 8; ++nt)
      bfr[nt] = *(const bf16x8*)(Bb + (nt * 16 + lm) * 32 + lq * 8);
#pragma unroll
    for (int mt = 0; mt < 4; ++mt)
#pragma unroll
      for (int nt = 0; nt < 8; ++nt)
        acc[mt][nt] = __builtin_amdgcn_mfma_f32_16x16x32_bf16(af[mt], bfr[nt], acc[mt][nt], 0, 0, 0);
  }

  const int lr = lq * 4;
  const int seg = N0 >> 11;               // 0:Q 1:K 2:V (uniform per block)
  const int nbase = N0 & 2047;
  const float* bb = (seg == 0) ? bq : ((seg == 1) ? bk : bv);
  if (seg < 2) {
    __bf16* dst = (seg == 0) ? Qout : Kout;
#pragma unroll
    for (int mt = 0; mt < 4; ++mt) {
#pragma unroll
      for (int nt = 0; nt < 8; ++nt) {
        const int col = nbase + nt * 16 + lm;
        const float bvv = bb[col];
#pragma unroll
        for (int i = 0; i < 4; ++i) {
          const int row = M0 + w * 64 + mt * 16 + lr + i;
          dst[(size_t)row * 2048 + col] = (__bf16)(acc[mt][nt][i] + bvv);
        }
      }
    }
  } else {
    // V transposed: Vt[(b*2048 + d)][token], b64-packed over 4 tokens
#pragma unroll
    for (int mt = 0; mt < 4; ++mt) {
#pragma unroll
      for (int nt = 0; nt < 8; ++nt) {
        const int col = nbase + nt * 16 + lm;
        const float bvv = bb[col];
        const int rw0 = M0 + w * 64 + mt * 16 + lr;
        const int bidx = rw0 >> 11, tok = rw0 & 2047;
        bf16x4v pk;
#pragma unroll
        for (int i = 0; i < 4; ++i) pk[i] = (__bf16)(acc[mt][nt][i] + bvv);
        *(bf16x4v*)(Vtout + ((size_t)(bidx * 2048 + col)) * 2048 + tok) = pk;
      }
    }
  }
}

// ---------- fused FFN GEMM: hn2 @ [W1t|W12t] -> fm = silu(x1)*x2 ----------
// 128x128 tile; tile cols 0..63 = x1 cols, 64..127 = x2 cols (same fm cols).
// Epilogue: wc=1 waves hand x2 accs to wc=0 waves through LDS; write fm only.
__global__ __launch_bounds__(256) void gemm_ffn(
    const __bf16* __restrict__ A, const __bf16* __restrict__ Bt,
    __bf16* __restrict__ FM, int Kd) {
  __shared__ __attribute__((aligned(16))) char SM[32768];
  const int tid = threadIdx.x;
  const int w = tid >> 6, l = tid & 63;
  const int M0 = blockIdx.y * 128, N0 = blockIdx.x * 128;
  const int wr = w >> 1, wc = w & 1;
  const int lm = l & 15, lq = l >> 4;

  f32x4 acc[4][4];
#pragma unroll
  for (int mt = 0; mt < 4; ++mt)
#pragma unroll
    for (int nt = 0; nt < 4; ++nt)
#pragma unroll
      for (int e = 0; e < 4; ++e) acc[mt][nt][e] = 0.f;

  const int srow = l >> 2, sk = (l & 3) * 16;
  const int nIt = Kd >> 5;

  auto stage = [&](int k0, int bsel) {
    char* Abuf = SM + bsel * 8192;
    char* Bbuf = SM + 16384 + bsel * 8192;
#pragma unroll
    for (int i = 0; i < 2; ++i) {
      const int c = w * 2 + i;
      const char* ga = (const char*)(A + (size_t)(M0 + c * 16 + srow) * Kd + k0) + sk;
      const char* gb = (const char*)(Bt + (size_t)(N0 + c * 16 + srow) * Kd + k0) + sk;
      __builtin_amdgcn_global_load_lds(GLB_AS(ga), LDS_AS(Abuf + c * 1024), 16, 0, 0);
      __builtin_amdgcn_global_load_lds(GLB_AS(gb), LDS_AS(Bbuf + c * 1024), 16, 0, 0);
    }
  };

  stage(0, 0);
  for (int it = 0; it < nIt; ++it) {
    __syncthreads();
    if (it + 1 < nIt) stage((it + 1) * 32, (it + 1) & 1);
    const __bf16* Ab = (const __bf16*)(SM + (it & 1) * 8192);
    const __bf16* Bb = (const __bf16*)(SM + 16384 + (it & 1) * 8192);
    bf16x8 af[4], bfr[4];
#pragma unroll
    for (int mt = 0; mt < 4; ++mt)
      af[mt] = *(const bf16x8*)(Ab + (wr * 64 + mt * 16 + lm) * 32 + lq * 8);
#pragma unroll
    for (int nt = 0; nt < 4; ++nt)
      bfr[nt] = *(const bf16x8*)(Bb + (wc * 64 + nt * 16 + lm) * 32 + lq * 8);
#pragma unroll
    for (int mt = 0; mt < 4; ++mt)
#pragma unroll
      for (int nt = 0; nt < 4; ++nt)
        acc[mt][nt] = __builtin_amdgcn_mfma_f32_16x16x32_bf16(af[mt], bfr[nt], acc[mt][nt], 0, 0, 0);
  }

  // epilogue: exchange x2 (wc=1) -> x1 (wc=0) through LDS, write fm
  __syncthreads();
  if (wc == 1) {
    float* dst = (float*)(SM + wr * 16384);
#pragma unroll
    for (int mt = 0; mt < 4; ++mt)
#pragma unroll
      for (int nt = 0; nt < 4; ++nt)
        *(f32x4*)(dst + ((mt * 4 + nt) * 64 + l) * 4) = acc[mt][nt];
  }
  __syncthreads();
  if (wc == 0) {
    const float* src = (const float*)(SM + wr * 16384);
    const int lr = lq * 4;
#pragma unroll
    for (int mt = 0; mt < 4; ++mt) {
#pragma unroll
      for (int nt = 0; nt < 4; ++nt) {
        const f32x4 x2 = *(const f32x4*)(src + ((mt * 4 + nt) * 64 + l) * 4);
        const int col = (N0 >> 1) + nt * 16 + lm;  // fm col = bx*64 + ...
#pragma unroll
        for (int i = 0; i < 4; ++i) {
          const int row = M0 + wr * 64 + mt * 16 + lr + i;
          const float x1 = acc[mt][nt][i];
          const float v = x1 * (1.f / (1.f + __expf(-x1))) * x2[i];
          FM[(size_t)row * 2048 + col] = (__bf16)v;
        }
      }
    }
  }
}

// ---------- MFMA flash attention v5 (unchanged) ----------
__global__ __launch_bounds__(256, 2) void attn_mfma(
    const __bf16* __restrict__ Q, const __bf16* __restrict__ K,
    const __bf16* __restrict__ Vt, __bf16* __restrict__ O) {
  __shared__ __attribute__((aligned(16))) char KsL[2][16 * 1024];
  __shared__ __attribute__((aligned(16))) char VsL[2][16 * 1024];

  const int t = threadIdx.x;
  const int w = t >> 6, l = t & 63;
  const int lm = l & 15, quad = l >> 4;
  const int h = blockIdx.y, b = blockIdx.z;
  const int q0 = blockIdx.x * 128;
  const size_t Ds = 2048;
  const size_t hoff = (size_t)h * 128;
  const size_t bbase = (size_t)b * 2048;
  const int sl16 = ((lm << 2) | quad) * 16;
  const float SCL = 0.08838834764831845f * 1.4426950408889634f;

  const int krow = l >> 2, kcol = (l & 3) * 8;
  const int vth = l & 3, vd = l >> 2;

  bf16x8 qf[2][4];
#pragma unroll
  for (int ntq = 0; ntq < 2; ++ntq)
#pragma unroll
    for (int ks = 0; ks < 4; ++ks)
      qf[ntq][ks] = *(const bf16x8*)(Q + (bbase + q0 + w * 32 + ntq * 16 + lm) * Ds + hoff + ks * 32 + quad * 8);

  f32x4 oacc[2][8];
#pragma unroll
  for (int ntq = 0; ntq < 2; ++ntq)
#pragma unroll
    for (int nv = 0; nv < 8; ++nv)
#pragma unroll
      for (int e = 0; e < 4; ++e) oacc[ntq][nv][e] = 0.f;
  float lpart[2] = {0.f, 0.f};

  bf16x8 vreg[4];

  auto loadV = [&](int kt) {
#pragma unroll
    for (int i = 0; i < 4; ++i) {
      const int chunk = w * 4 + i;
      const int nv = chunk >> 1, c = chunk & 1;
      vreg[i] = *(const bf16x8*)(Vt + (bbase + hoff + nv * 16 + vd) * Ds + kt + c * 32 + vth * 8);
    }
  };
  auto stageK = [&](int kt, char* Kb) {
#pragma unroll
    for (int i = 0; i < 4; ++i) {
      const __bf16* src = K + (bbase + kt + i * 16 + krow) * Ds + hoff + w * 32 + kcol;
      __builtin_amdgcn_global_load_lds(GLB_AS(src), LDS_AS(Kb + (i * 4 + w) * 1024), 16, 0, 0);
    }
  };
  auto writeV = [&](char* Vb) {
    const int s0off = ((vd << 2) | ((vth & 1) * 2)) * 16 + (vth >> 1) * 8;
#pragma unroll
    for (int i = 0; i < 4; ++i) {
      char* base = Vb + (w * 4 + i) * 1024;
      uint4 u = *(const uint4*)&vreg[i];
      *(uint2*)(base + s0off) = make_uint2(u.x, u.y);
      *(uint2*)(base + s0off + 16) = make_uint2(u.z, u.w);
    }
  };

  loadV(0);
  stageK(0, KsL[0]);
  writeV(VsL[0]);

  for (int it = 0; it < 32; ++it) {
    __syncthreads();
    const int cur = it & 1;
    const bool more = (it + 1) < 32;
    if (more) { loadV((it + 1) * 64); stageK((it + 1) * 64, KsL[(it + 1) & 1]); }

    const char* Kb = KsL[cur];
    const char* Vb = VsL[cur];

    f32x4 st[4][2];
#pragma unroll
    for (int mtk = 0; mtk < 4; ++mtk)
#pragma unroll
      for (int ntq = 0; ntq < 2; ++ntq)
#pragma unroll
        for (int e = 0; e < 4; ++e) st[mtk][ntq][e] = 0.f;
#pragma unroll
    for (int ks = 0; ks < 4; ++ks) {
#pragma unroll
      for (int mtk = 0; mtk < 4; ++mtk) {
        bf16x8 kf = *(const bf16x8*)(Kb + (mtk * 4 + ks) * 1024 + sl16);
        st[mtk][0] = __builtin_amdgcn_mfma_f32_16x16x32_bf16(kf, qf[0][ks], st[mtk][0], 0, 0, 0);
        st[mtk][1] = __builtin_amdgcn_mfma_f32_16x16x32_bf16(kf, qf[1][ks], st[mtk][1], 0, 0, 0);
      }
    }

#pragma unroll
    for (int c = 0; c < 2; ++c) {
      bf16x8 pf[2];
#pragma unroll
      for (int ntq = 0; ntq < 2; ++ntq) {
#pragma unroll
        for (int half = 0; half < 2; ++half) {
          const f32x4 sv = st[c * 2 + half][ntq];
#pragma unroll
          for (int r = 0; r < 4; ++r) {
            const float p = exp2f(sv[r] * SCL);
            const __bf16 pb = (__bf16)p;
            pf[ntq][half * 4 + r] = pb;
            lpart[ntq] += (float)pb;
          }
        }
      }
#pragma unroll
      for (int nv = 0; nv < 8; ++nv) {
        bf16x8 vf = *(const bf16x8*)(Vb + (nv * 2 + c) * 1024 + sl16);
        oacc[0][nv] = __builtin_amdgcn_mfma_f32_16x16x32_bf16(pf[0], vf, oacc[0][nv], 0, 0, 0);
        oacc[1][nv] = __builtin_amdgcn_mfma_f32_16x16x32_bf16(pf[1], vf, oacc[1][nv], 0, 0, 0);
      }
    }

    if (more) writeV(VsL[(it + 1) & 1]);
  }

  float linv[2];
#pragma unroll
  for (int ntq = 0; ntq < 2; ++ntq) {
    float v = lpart[ntq];
    v += __shfl_xor(v, 16, 64);
    v += __shfl_xor(v, 32, 64);
    linv[ntq] = 1.f / v;
  }
  float oinv[2][4];
#pragma unroll
  for (int ntq = 0; ntq < 2; ++ntq)
#pragma unroll
    for (int r = 0; r < 4; ++r)
      oinv[ntq][r] = __shfl(linv[ntq], quad * 4 + r, 64);

#pragma unroll
  for (int ntq = 0; ntq < 2; ++ntq)
#pragma unroll
    for (int nv = 0; nv < 8; ++nv)
#pragma unroll
      for (int r = 0; r < 4; ++r) {
        const int qrow = q0 + w * 32 + ntq * 16 + quad * 4 + r;
        O[(bbase + qrow) * Ds + hoff + nv * 16 + lm] = (__bf16)(oacc[ntq][nv][r] * oinv[ntq][r]);
      }
}

// ---------- launch ----------
extern "C" void kernel_launch(void* const* d_in, const int* in_sizes, int n_in,
                              void* d_out, int out_size, void* d_ws, size_t ws_size,
                              hipStream_t stream) {
  const float* x      = (const float*)d_in[0];
  const float* Wq     = (const float*)d_in[1];
  const float* bq     = (const float*)d_in[2];
  const float* Wk     = (const float*)d_in[3];
  const float* bk     = (const float*)d_in[4];
  const float* Wv     = (const float*)d_in[5];
  const float* bv     = (const float*)d_in[6];
  const float* Wo     = (const float*)d_in[7];
  const float* bo     = (const float*)d_in[8];
  const float* scale1 = (const float*)d_in[9];
  const float* scale2 = (const float*)d_in[10];
  const float* W1     = (const float*)d_in[11];
  const float* W2     = (const float*)d_in[12];
  const float* W3     = (const float*)d_in[13];

  const int M = 4096, N = 2048, Kd = 2048;
  char* ws = (char*)d_ws;
  const size_t WT_B = (size_t)2048 * 2048 * 2;   // 8 MB
  const size_t ACT_B = (size_t)4096 * 2048 * 2;  // 16 MB
  __bf16* wt[7];
  size_t off = 0;
  for (int i = 0; i < 7; ++i) { wt[i] = (__bf16*)(ws + off); off += WT_B; }
  __bf16* hn1   = (__bf16*)(ws + off); off += ACT_B;
  __bf16* Qb    = (__bf16*)(ws + off); off += ACT_B;
  __bf16* Kb    = (__bf16*)(ws + off); off += ACT_B;
  __bf16* VtG   = (__bf16*)(ws + off); off += ACT_B;
  __bf16* attn  = (__bf16*)(ws + off); off += ACT_B;
  __bf16* hn2   = (__bf16*)(ws + off); off += ACT_B;
  __bf16* BtFFN = (__bf16*)(ws + off); off += ACT_B;
  __bf16* fmb   = (__bf16*)(ws + off); off += ACT_B;
  // transient aliases (dead before QKV writes Qb/Kb):
  __bf16* W1b  = Qb;   // bf16 copy of W1 (non-transposed), 8 MB
  __bf16* W12t = Kb;   // W12t = (W1@W2)^T, 8 MB

  dim3 tb(256);
  {
    TP p;
    p.s[0] = Wq; p.s[1] = Wk; p.s[2] = Wv; p.s[3] = Wo; p.s[4] = W1; p.s[5] = W2; p.s[6] = W3;
    for (int i = 0; i < 7; ++i) p.d[i] = wt[i];
    p.w1b = W1b;
    transpose_convert_all<<<dim3(64, 64, 7), tb, 0, stream>>>(p);
  }

  // W12t[m][n] = sum_j W2t[m][j] * W1b[n][j]  ( = (W1@W2)^T )
  gemm_bt<false, false, false><<<dim3(16, 16), tb, 0, stream>>>(
      wt[5], W1b, nullptr, nullptr, W12t, 2048, 2048, 2048);
  ffn_interleave<<<4096, tb, 0, stream>>>(wt[4], W12t, BtFFN);

  rmsnorm_k<<<4096, tb, 0, stream>>>(x, scale1, hn1);

  // fused QKV GEMM: Bt = wt[0..2] contiguous = [6144][2048], 256x128 tiles
  gemm_qkv<<<dim3(6144 / 128, M / 256), tb, 0, stream>>>(
      hn1, wt[0], bq, bk, bv, Qb, Kb, VtG, Kd);

  dim3 ag(2048 / 128, 16, 2);
  attn_mfma<<<ag, tb, 0, stream>>>(Qb, Kb, VtG, attn);

  dim3 gg(N / 128, M / 128);
  // h2 = x + attn@Wo + bo  -> d_out (f32 scratch)
  gemm_bt<true, true, true><<<gg, tb, 0, stream>>>(attn, wt[3], bo, x, d_out, M, N, Kd);

  rmsnorm_k<<<4096, tb, 0, stream>>>((const float*)d_out, scale2, hn2);

  // fm = silu(hn2@W1) * (hn2@W12)  in one GEMM over BtFFN[4096][2048]
  gemm_ffn<<<dim3(32, 32), tb, 0, stream>>>(hn2, BtFFN, fmb, Kd);

  // out = fm@W3 + x
  gemm_bt<true, false, true><<<gg, tb, 0, stream>>>(fmb, wt[6], nullptr, x, d_out, M, N, Kd);
}

// Round 7
// 688.683 us; speedup vs baseline: 1.0713x; 1.0713x over previous
//
#include <hip/hip_runtime.h>

// ---------- types ----------
typedef __bf16 bf16x8 __attribute__((ext_vector_type(8)));
typedef __bf16 bf16x4v __attribute__((ext_vector_type(4)));
typedef float  f32x4  __attribute__((ext_vector_type(4)));

#define LDS_AS(p) ((__attribute__((address_space(3))) void*)(p))
#define GLB_AS(p) ((const __attribute__((address_space(1))) void*)(p))

// ---------- batched weight f32 -> bf16 transposed ----------
// z==4 (W1): transposed rows go DIRECTLY into BtFFN interleaved first-halves
//            ( row n -> (n>>6)*128 + (n&63) ), plus plain bf16 copy W1b.
struct TP { const float* s[7]; __bf16* d[7]; __bf16* w1b; __bf16* btffn; };
__global__ __launch_bounds__(256) void transpose_convert_all(TP p) {
  const float* __restrict__ W = p.s[blockIdx.z];
  __shared__ float tile[32][33];
  const int tx = threadIdx.x & 31, ty = threadIdx.x >> 5;
  const int n0 = blockIdx.x * 32, k0 = blockIdx.y * 32;
#pragma unroll
  for (int j = 0; j < 4; ++j)
    tile[ty + j * 8][tx] = W[(size_t)(k0 + ty + j * 8) * 2048 + n0 + tx];
  __syncthreads();
  if (blockIdx.z == 4) {
#pragma unroll
    for (int j = 0; j < 4; ++j) {
      const int n = n0 + ty + j * 8;
      const int btrow = ((n >> 6) << 7) + (n & 63);
      p.btffn[(size_t)btrow * 2048 + k0 + tx] = (__bf16)tile[tx][ty + j * 8];
      p.w1b[(size_t)(k0 + ty + j * 8) * 2048 + n0 + tx] = (__bf16)tile[ty + j * 8][tx];
    }
  } else {
    __bf16* __restrict__ Wt = p.d[blockIdx.z];
#pragma unroll
    for (int j = 0; j < 4; ++j)
      Wt[(size_t)(n0 + ty + j * 8) * 2048 + k0 + tx] = (__bf16)tile[tx][ty + j * 8];
  }
}

// ---------- RMSNorm: f32 in -> bf16 out, D=2048, one block per row ----------
__global__ __launch_bounds__(256) void rmsnorm_k(
    const float* __restrict__ x, const float* __restrict__ scale,
    __bf16* __restrict__ out) {
  const int row = blockIdx.x, t = threadIdx.x;
  const float4* xr = (const float4*)(x + (size_t)row * 2048);
  float4 a = xr[t], b2 = xr[t + 256];
  float ss = a.x * a.x + a.y * a.y + a.z * a.z + a.w * a.w +
             b2.x * b2.x + b2.y * b2.y + b2.z * b2.z + b2.w * b2.w;
#pragma unroll
  for (int ofs = 32; ofs; ofs >>= 1) ss += __shfl_xor(ss, ofs, 64);
  __shared__ float red[4];
  if ((t & 63) == 0) red[t >> 6] = ss;
  __syncthreads();
  ss = red[0] + red[1] + red[2] + red[3];
  const float rs = rsqrtf(ss * (1.f / 2048.f) + 1e-5f);
  const float4* sr = (const float4*)scale;
  float4 s1 = sr[t], s2 = sr[t + 256];
  __bf16* orow = out + (size_t)row * 2048;
  orow[t * 4 + 0] = (__bf16)(a.x * rs * s1.x);
  orow[t * 4 + 1] = (__bf16)(a.y * rs * s1.y);
  orow[t * 4 + 2] = (__bf16)(a.z * rs * s1.z);
  orow[t * 4 + 3] = (__bf16)(a.w * rs * s1.w);
  orow[(t + 256) * 4 + 0] = (__bf16)(b2.x * rs * s2.x);
  orow[(t + 256) * 4 + 1] = (__bf16)(b2.y * rs * s2.y);
  orow[(t + 256) * 4 + 2] = (__bf16)(b2.z * rs * s2.z);
  orow[(t + 256) * 4 + 3] = (__bf16)(b2.w * rs * s2.w);
}

// ---------- gemm64: 64x128 tile, dbuf, grid-rich GEMM ----------
// wave (wr=w>>1, wc=w&1) computes rows wr*32+mt*16, cols wc*64+nt*16 (2x4 accs).
// W12MAP: bf16 out, row remapped into BtFFN second-half ((m>>6)*128+64+(m&63)).
template <bool HASBIAS, bool HASRES, bool W12MAP>
__global__ __launch_bounds__(256) void gemm64(
    const __bf16* __restrict__ A, const __bf16* __restrict__ Bt,
    const float* __restrict__ bias, const float* __restrict__ res,
    void* __restrict__ Cout, int M, int N, int Kd) {
  __shared__ __attribute__((aligned(16))) __bf16 As[2][64 * 32];    // 4 KB x2
  __shared__ __attribute__((aligned(16))) __bf16 Bs[2][128 * 32];   // 8 KB x2
  const int tid = threadIdx.x;
  const int w = tid >> 6, l = tid & 63;
  const int M0 = blockIdx.y * 64, N0 = blockIdx.x * 128;
  const int wr = w >> 1, wc = w & 1;
  const int lm = l & 15, lq = l >> 4;

  f32x4 acc[2][4];
#pragma unroll
  for (int mt = 0; mt < 2; ++mt)
#pragma unroll
    for (int nt = 0; nt < 4; ++nt)
#pragma unroll
      for (int e = 0; e < 4; ++e) acc[mt][nt][e] = 0.f;

  const int srow = l >> 2, sk = (l & 3) * 16;
  const int nIt = Kd >> 5;

  auto stage = [&](int k0, int bsel) {
#pragma unroll
    for (int i = 0; i < 3; ++i) {          // 12 chunks: 4 A + 8 B, 3 per wave
      const int c = w * 3 + i;
      if (c < 4) {
        const char* ga = (const char*)(A + (size_t)(M0 + c * 16 + srow) * Kd + k0) + sk;
        __builtin_amdgcn_global_load_lds(GLB_AS(ga), LDS_AS(((char*)As[bsel]) + c * 1024), 16, 0, 0);
      } else {
        const char* gb = (const char*)(Bt + (size_t)(N0 + (c - 4) * 16 + srow) * Kd + k0) + sk;
        __builtin_amdgcn_global_load_lds(GLB_AS(gb), LDS_AS(((char*)Bs[bsel]) + (c - 4) * 1024), 16, 0, 0);
      }
    }
  };

  stage(0, 0);
  for (int it = 0; it < nIt; ++it) {
    __syncthreads();
    if (it + 1 < nIt) stage((it + 1) * 32, (it + 1) & 1);
    const __bf16* Ab = As[it & 1];
    const __bf16* Bb = Bs[it & 1];
    bf16x8 af[2], bfr[4];
#pragma unroll
    for (int mt = 0; mt < 2; ++mt)
      af[mt] = *(const bf16x8*)(Ab + (wr * 32 + mt * 16 + lm) * 32 + lq * 8);
#pragma unroll
    for (int nt = 0; nt < 4; ++nt)
      bfr[nt] = *(const bf16x8*)(Bb + (wc * 64 + nt * 16 + lm) * 32 + lq * 8);
#pragma unroll
    for (int mt = 0; mt < 2; ++mt)
#pragma unroll
      for (int nt = 0; nt < 4; ++nt)
        acc[mt][nt] = __builtin_amdgcn_mfma_f32_16x16x32_bf16(af[mt], bfr[nt], acc[mt][nt], 0, 0, 0);
  }

  const int lr = lq * 4;
#pragma unroll
  for (int mt = 0; mt < 2; ++mt) {
#pragma unroll
    for (int nt = 0; nt < 4; ++nt) {
      const int col = N0 + wc * 64 + nt * 16 + lm;
      float bv = 0.f;
      if (HASBIAS) bv = bias[col];
#pragma unroll
      for (int i = 0; i < 4; ++i) {
        const int row = M0 + wr * 32 + mt * 16 + lr + i;
        float v = acc[mt][nt][i] + bv;
        if (W12MAP) {
          const int rr = ((row >> 6) << 7) + 64 + (row & 63);
          ((__bf16*)Cout)[(size_t)rr * 2048 + col] = (__bf16)v;
        } else {
          const size_t off = (size_t)row * N + col;
          if (HASRES) v += res[off];
          ((float*)Cout)[off] = v;
        }
      }
    }
  }
}

// ---------- fused QKV GEMM, 128x128 tile (round-4 config) ----------
__global__ __launch_bounds__(256) void gemm_qkv(
    const __bf16* __restrict__ A, const __bf16* __restrict__ Bt,
    const float* __restrict__ bq, const float* __restrict__ bk,
    const float* __restrict__ bv,
    __bf16* __restrict__ Qout, __bf16* __restrict__ Kout,
    __bf16* __restrict__ Vtout, int Kd) {
  __shared__ __attribute__((aligned(16))) __bf16 As[2][128 * 32];
  __shared__ __attribute__((aligned(16))) __bf16 Bs[2][128 * 32];
  const int tid = threadIdx.x;
  const int w = tid >> 6, l = tid & 63;
  const int M0 = blockIdx.y * 128, N0 = blockIdx.x * 128;
  const int wr = w >> 1, wc = w & 1;
  const int lm = l & 15, lq = l >> 4;

  f32x4 acc[4][4];
#pragma unroll
  for (int mt = 0; mt < 4; ++mt)
#pragma unroll
    for (int nt = 0; nt < 4; ++nt)
#pragma unroll
      for (int e = 0; e < 4; ++e) acc[mt][nt][e] = 0.f;

  const int srow = l >> 2, sk = (l & 3) * 16;
  const int nIt = Kd >> 5;

  auto stage = [&](int k0, int bsel) {
#pragma unroll
    for (int i = 0; i < 2; ++i) {
      const int c = w * 2 + i;
      const char* ga = (const char*)(A + (size_t)(M0 + c * 16 + srow) * Kd + k0) + sk;
      const char* gb = (const char*)(Bt + (size_t)(N0 + c * 16 + srow) * Kd + k0) + sk;
      __builtin_amdgcn_global_load_lds(GLB_AS(ga), LDS_AS(((char*)As[bsel]) + c * 1024), 16, 0, 0);
      __builtin_amdgcn_global_load_lds(GLB_AS(gb), LDS_AS(((char*)Bs[bsel]) + c * 1024), 16, 0, 0);
    }
  };

  stage(0, 0);
  for (int it = 0; it < nIt; ++it) {
    __syncthreads();
    if (it + 1 < nIt) stage((it + 1) * 32, (it + 1) & 1);
    const __bf16* Ab = As[it & 1];
    const __bf16* Bb = Bs[it & 1];
    bf16x8 af[4], bfr[4];
#pragma unroll
    for (int mt = 0; mt < 4; ++mt)
      af[mt] = *(const bf16x8*)(Ab + (wr * 64 + mt * 16 + lm) * 32 + lq * 8);
#pragma unroll
    for (int nt = 0; nt < 4; ++nt)
      bfr[nt] = *(const bf16x8*)(Bb + (wc * 64 + nt * 16 + lm) * 32 + lq * 8);
#pragma unroll
    for (int mt = 0; mt < 4; ++mt)
#pragma unroll
      for (int nt = 0; nt < 4; ++nt)
        acc[mt][nt] = __builtin_amdgcn_mfma_f32_16x16x32_bf16(af[mt], bfr[nt], acc[mt][nt], 0, 0, 0);
  }

  const int lr = lq * 4;
  const int seg = N0 >> 11;               // 0:Q 1:K 2:V (uniform per block)
  const int nbase = N0 & 2047;
  const float* bb = (seg == 0) ? bq : ((seg == 1) ? bk : bv);
  if (seg < 2) {
    __bf16* dst = (seg == 0) ? Qout : Kout;
#pragma unroll
    for (int mt = 0; mt < 4; ++mt) {
#pragma unroll
      for (int nt = 0; nt < 4; ++nt) {
        const int col = nbase + wc * 64 + nt * 16 + lm;
        const float bvv = bb[col];
#pragma unroll
        for (int i = 0; i < 4; ++i) {
          const int row = M0 + wr * 64 + mt * 16 + lr + i;
          dst[(size_t)row * 2048 + col] = (__bf16)(acc[mt][nt][i] + bvv);
        }
      }
    }
  } else {
#pragma unroll
    for (int mt = 0; mt < 4; ++mt) {
#pragma unroll
      for (int nt = 0; nt < 4; ++nt) {
        const int col = nbase + wc * 64 + nt * 16 + lm;
        const float bvv = bb[col];
        const int rw0 = M0 + wr * 64 + mt * 16 + lr;
        const int bidx = rw0 >> 11, tok = rw0 & 2047;
        bf16x4v pk;
#pragma unroll
        for (int i = 0; i < 4; ++i) pk[i] = (__bf16)(acc[mt][nt][i] + bvv);
        *(bf16x4v*)(Vtout + ((size_t)(bidx * 2048 + col)) * 2048 + tok) = pk;
      }
    }
  }
}

// ---------- fused FFN GEMM: hn2 @ BtFFN[4096][2048] -> fm = silu(x1)*x2 -----
__global__ __launch_bounds__(256) void gemm_ffn(
    const __bf16* __restrict__ A, const __bf16* __restrict__ Bt,
    __bf16* __restrict__ FM, int Kd) {
  __shared__ __attribute__((aligned(16))) char SM[32768];
  const int tid = threadIdx.x;
  const int w = tid >> 6, l = tid & 63;
  const int M0 = blockIdx.y * 128, N0 = blockIdx.x * 128;
  const int wr = w >> 1, wc = w & 1;
  const int lm = l & 15, lq = l >> 4;

  f32x4 acc[4][4];
#pragma unroll
  for (int mt = 0; mt < 4; ++mt)
#pragma unroll
    for (int nt = 0; nt < 4; ++nt)
#pragma unroll
      for (int e = 0; e < 4; ++e) acc[mt][nt][e] = 0.f;

  const int srow = l >> 2, sk = (l & 3) * 16;
  const int nIt = Kd >> 5;

  auto stage = [&](int k0, int bsel) {
    char* Abuf = SM + bsel * 8192;
    char* Bbuf = SM + 16384 + bsel * 8192;
#pragma unroll
    for (int i = 0; i < 2; ++i) {
      const int c = w * 2 + i;
      const char* ga = (const char*)(A + (size_t)(M0 + c * 16 + srow) * Kd + k0) + sk;
      const char* gb = (const char*)(Bt + (size_t)(N0 + c * 16 + srow) * Kd + k0) + sk;
      __builtin_amdgcn_global_load_lds(GLB_AS(ga), LDS_AS(Abuf + c * 1024), 16, 0, 0);
      __builtin_amdgcn_global_load_lds(GLB_AS(gb), LDS_AS(Bbuf + c * 1024), 16, 0, 0);
    }
  };

  stage(0, 0);
  for (int it = 0; it < nIt; ++it) {
    __syncthreads();
    if (it + 1 < nIt) stage((it + 1) * 32, (it + 1) & 1);
    const __bf16* Ab = (const __bf16*)(SM + (it & 1) * 8192);
    const __bf16* Bb = (const __bf16*)(SM + 16384 + (it & 1) * 8192);
    bf16x8 af[4], bfr[4];
#pragma unroll
    for (int mt = 0; mt < 4; ++mt)
      af[mt] = *(const bf16x8*)(Ab + (wr * 64 + mt * 16 + lm) * 32 + lq * 8);
#pragma unroll
    for (int nt = 0; nt < 4; ++nt)
      bfr[nt] = *(const bf16x8*)(Bb + (wc * 64 + nt * 16 + lm) * 32 + lq * 8);
#pragma unroll
    for (int mt = 0; mt < 4; ++mt)
#pragma unroll
      for (int nt = 0; nt < 4; ++nt)
        acc[mt][nt] = __builtin_amdgcn_mfma_f32_16x16x32_bf16(af[mt], bfr[nt], acc[mt][nt], 0, 0, 0);
  }

  // epilogue: exchange x2 (wc=1) -> x1 (wc=0) through LDS, write fm
  __syncthreads();
  if (wc == 1) {
    float* dst = (float*)(SM + wr * 16384);
#pragma unroll
    for (int mt = 0; mt < 4; ++mt)
#pragma unroll
      for (int nt = 0; nt < 4; ++nt)
        *(f32x4*)(dst + ((mt * 4 + nt) * 64 + l) * 4) = acc[mt][nt];
  }
  __syncthreads();
  if (wc == 0) {
    const float* src = (const float*)(SM + wr * 16384);
    const int lr = lq * 4;
#pragma unroll
    for (int mt = 0; mt < 4; ++mt) {
#pragma unroll
      for (int nt = 0; nt < 4; ++nt) {
        const f32x4 x2 = *(const f32x4*)(src + ((mt * 4 + nt) * 64 + l) * 4);
        const int col = (N0 >> 1) + nt * 16 + lm;
#pragma unroll
        for (int i = 0; i < 4; ++i) {
          const int row = M0 + wr * 64 + mt * 16 + lr + i;
          const float x1 = acc[mt][nt][i];
          const float v = x1 * (1.f / (1.f + __expf(-x1))) * x2[i];
          FM[(size_t)row * 2048 + col] = (__bf16)v;
        }
      }
    }
  }
}

// ---------- MFMA flash attention v5 (unchanged) ----------
__global__ __launch_bounds__(256, 2) void attn_mfma(
    const __bf16* __restrict__ Q, const __bf16* __restrict__ K,
    const __bf16* __restrict__ Vt, __bf16* __restrict__ O) {
  __shared__ __attribute__((aligned(16))) char KsL[2][16 * 1024];
  __shared__ __attribute__((aligned(16))) char VsL[2][16 * 1024];

  const int t = threadIdx.x;
  const int w = t >> 6, l = t & 63;
  const int lm = l & 15, quad = l >> 4;
  const int h = blockIdx.y, b = blockIdx.z;
  const int q0 = blockIdx.x * 128;
  const size_t Ds = 2048;
  const size_t hoff = (size_t)h * 128;
  const size_t bbase = (size_t)b * 2048;
  const int sl16 = ((lm << 2) | quad) * 16;
  const float SCL = 0.08838834764831845f * 1.4426950408889634f;

  const int krow = l >> 2, kcol = (l & 3) * 8;
  const int vth = l & 3, vd = l >> 2;

  bf16x8 qf[2][4];
#pragma unroll
  for (int ntq = 0; ntq < 2; ++ntq)
#pragma unroll
    for (int ks = 0; ks < 4; ++ks)
      qf[ntq][ks] = *(const bf16x8*)(Q + (bbase + q0 + w * 32 + ntq * 16 + lm) * Ds + hoff + ks * 32 + quad * 8);

  f32x4 oacc[2][8];
#pragma unroll
  for (int ntq = 0; ntq < 2; ++ntq)
#pragma unroll
    for (int nv = 0; nv < 8; ++nv)
#pragma unroll
      for (int e = 0; e < 4; ++e) oacc[ntq][nv][e] = 0.f;
  float lpart[2] = {0.f, 0.f};

  bf16x8 vreg[4];

  auto loadV = [&](int kt) {
#pragma unroll
    for (int i = 0; i < 4; ++i) {
      const int chunk = w * 4 + i;
      const int nv = chunk >> 1, c = chunk & 1;
      vreg[i] = *(const bf16x8*)(Vt + (bbase + hoff + nv * 16 + vd) * Ds + kt + c * 32 + vth * 8);
    }
  };
  auto stageK = [&](int kt, char* Kb) {
#pragma unroll
    for (int i = 0; i < 4; ++i) {
      const __bf16* src = K + (bbase + kt + i * 16 + krow) * Ds + hoff + w * 32 + kcol;
      __builtin_amdgcn_global_load_lds(GLB_AS(src), LDS_AS(Kb + (i * 4 + w) * 1024), 16, 0, 0);
    }
  };
  auto writeV = [&](char* Vb) {
    const int s0off = ((vd << 2) | ((vth & 1) * 2)) * 16 + (vth >> 1) * 8;
#pragma unroll
    for (int i = 0; i < 4; ++i) {
      char* base = Vb + (w * 4 + i) * 1024;
      uint4 u = *(const uint4*)&vreg[i];
      *(uint2*)(base + s0off) = make_uint2(u.x, u.y);
      *(uint2*)(base + s0off + 16) = make_uint2(u.z, u.w);
    }
  };

  loadV(0);
  stageK(0, KsL[0]);
  writeV(VsL[0]);

  for (int it = 0; it < 32; ++it) {
    __syncthreads();
    const int cur = it & 1;
    const bool more = (it + 1) < 32;
    if (more) { loadV((it + 1) * 64); stageK((it + 1) * 64, KsL[(it + 1) & 1]); }

    const char* Kb = KsL[cur];
    const char* Vb = VsL[cur];

    f32x4 st[4][2];
#pragma unroll
    for (int mtk = 0; mtk < 4; ++mtk)
#pragma unroll
      for (int ntq = 0; ntq < 2; ++ntq)
#pragma unroll
        for (int e = 0; e < 4; ++e) st[mtk][ntq][e] = 0.f;
#pragma unroll
    for (int ks = 0; ks < 4; ++ks) {
#pragma unroll
      for (int mtk = 0; mtk < 4; ++mtk) {
        bf16x8 kf = *(const bf16x8*)(Kb + (mtk * 4 + ks) * 1024 + sl16);
        st[mtk][0] = __builtin_amdgcn_mfma_f32_16x16x32_bf16(kf, qf[0][ks], st[mtk][0], 0, 0, 0);
        st[mtk][1] = __builtin_amdgcn_mfma_f32_16x16x32_bf16(kf, qf[1][ks], st[mtk][1], 0, 0, 0);
      }
    }

#pragma unroll
    for (int c = 0; c < 2; ++c) {
      bf16x8 pf[2];
#pragma unroll
      for (int ntq = 0; ntq < 2; ++ntq) {
#pragma unroll
        for (int half = 0; half < 2; ++half) {
          const f32x4 sv = st[c * 2 + half][ntq];
#pragma unroll
          for (int r = 0; r < 4; ++r) {
            const float p = exp2f(sv[r] * SCL);
            const __bf16 pb = (__bf16)p;
            pf[ntq][half * 4 + r] = pb;
            lpart[ntq] += (float)pb;
          }
        }
      }
#pragma unroll
      for (int nv = 0; nv < 8; ++nv) {
        bf16x8 vf = *(const bf16x8*)(Vb + (nv * 2 + c) * 1024 + sl16);
        oacc[0][nv] = __builtin_amdgcn_mfma_f32_16x16x32_bf16(pf[0], vf, oacc[0][nv], 0, 0, 0);
        oacc[1][nv] = __builtin_amdgcn_mfma_f32_16x16x32_bf16(pf[1], vf, oacc[1][nv], 0, 0, 0);
      }
    }

    if (more) writeV(VsL[(it + 1) & 1]);
  }

  float linv[2];
#pragma unroll
  for (int ntq = 0; ntq < 2; ++ntq) {
    float v = lpart[ntq];
    v += __shfl_xor(v, 16, 64);
    v += __shfl_xor(v, 32, 64);
    linv[ntq] = 1.f / v;
  }
  float oinv[2][4];
#pragma unroll
  for (int ntq = 0; ntq < 2; ++ntq)
#pragma unroll
    for (int r = 0; r < 4; ++r)
      oinv[ntq][r] = __shfl(linv[ntq], quad * 4 + r, 64);

#pragma unroll
  for (int ntq = 0; ntq < 2; ++ntq)
#pragma unroll
    for (int nv = 0; nv < 8; ++nv)
#pragma unroll
      for (int r = 0; r < 4; ++r) {
        const int qrow = q0 + w * 32 + ntq * 16 + quad * 4 + r;
        O[(bbase + qrow) * Ds + hoff + nv * 16 + lm] = (__bf16)(oacc[ntq][nv][r] * oinv[ntq][r]);
      }
}

// ---------- launch ----------
extern "C" void kernel_launch(void* const* d_in, const int* in_sizes, int n_in,
                              void* d_out, int out_size, void* d_ws, size_t ws_size,
                              hipStream_t stream) {
  const float* x      = (const float*)d_in[0];
  const float* Wq     = (const float*)d_in[1];
  const float* bq     = (const float*)d_in[2];
  const float* Wk     = (const float*)d_in[3];
  const float* bk     = (const float*)d_in[4];
  const float* Wv     = (const float*)d_in[5];
  const float* bv     = (const float*)d_in[6];
  const float* Wo     = (const float*)d_in[7];
  const float* bo     = (const float*)d_in[8];
  const float* scale1 = (const float*)d_in[9];
  const float* scale2 = (const float*)d_in[10];
  const float* W1     = (const float*)d_in[11];
  const float* W2     = (const float*)d_in[12];
  const float* W3     = (const float*)d_in[13];

  const int M = 4096, Kd = 2048;
  char* ws = (char*)d_ws;
  const size_t WT_B = (size_t)2048 * 2048 * 2;   // 8 MB
  const size_t ACT_B = (size_t)4096 * 2048 * 2;  // 16 MB
  __bf16* wt[7];
  size_t off = 0;
  for (int i = 0; i < 7; ++i) { wt[i] = (__bf16*)(ws + off); off += WT_B; }
  __bf16* hn1   = (__bf16*)(ws + off); off += ACT_B;
  __bf16* Qb    = (__bf16*)(ws + off); off += ACT_B;
  __bf16* Kb    = (__bf16*)(ws + off); off += ACT_B;
  __bf16* VtG   = (__bf16*)(ws + off); off += ACT_B;
  __bf16* attn  = (__bf16*)(ws + off); off += ACT_B;
  __bf16* hn2   = (__bf16*)(ws + off); off += ACT_B;
  __bf16* BtFFN = (__bf16*)(ws + off); off += ACT_B;
  __bf16* fmb   = (__bf16*)(ws + off); off += ACT_B;
  // transient alias (dead before QKV writes Qb):
  __bf16* W1b  = Qb;   // bf16 copy of W1 (non-transposed), 8 MB

  dim3 tb(256);
  {
    TP p;
    p.s[0] = Wq; p.s[1] = Wk; p.s[2] = Wv; p.s[3] = Wo; p.s[4] = W1; p.s[5] = W2; p.s[6] = W3;
    for (int i = 0; i < 7; ++i) p.d[i] = wt[i];
    p.w1b = W1b; p.btffn = BtFFN;
    transpose_convert_all<<<dim3(64, 64, 7), tb, 0, stream>>>(p);
  }

  // W12t[m][n] = sum_j W2t[m][j]*W1b[n][j], written straight into BtFFN 2nd halves
  gemm64<false, false, true><<<dim3(16, 32), tb, 0, stream>>>(
      wt[5], W1b, nullptr, nullptr, BtFFN, 2048, 2048, Kd);

  rmsnorm_k<<<4096, tb, 0, stream>>>(x, scale1, hn1);

  // fused QKV GEMM: Bt = wt[0..2] contiguous = [6144][2048]
  gemm_qkv<<<dim3(48, 32), tb, 0, stream>>>(hn1, wt[0], bq, bk, bv, Qb, Kb, VtG, Kd);

  attn_mfma<<<dim3(16, 16, 2), tb, 0, stream>>>(Qb, Kb, VtG, attn);

  // h2 = x + attn@Wo + bo  -> d_out (f32 scratch)
  gemm64<true, true, false><<<dim3(16, 64), tb, 0, stream>>>(
      attn, wt[3], bo, x, d_out, M, 2048, Kd);

  rmsnorm_k<<<4096, tb, 0, stream>>>((const float*)d_out, scale2, hn2);

  // fm = silu(hn2@W1) * (hn2@W12) in one GEMM over BtFFN[4096][2048]
  gemm_ffn<<<dim3(32, 32), tb, 0, stream>>>(hn2, BtFFN, fmb, Kd);

  // out = fm@W3 + x
  gemm64<false, true, false><<<dim3(16, 64), tb, 0, stream>>>(
      fmb, wt[6], nullptr, x, d_out, M, 2048, Kd);
}